// Round 3
// baseline (1107.517 us; speedup 1.0000x reference)
//
#include <hip/hip_runtime.h>
#include <cstdint>
#include <cstddef>

#define T_SEQ 2048
#define B_SZ  8
#define F_DIM 768
#define H_CNT 3
#define DH    256

typedef float floatx4 __attribute__((ext_vector_type(4)));
typedef short bf16x8  __attribute__((ext_vector_type(8)));

static __device__ __forceinline__ unsigned short f2bf(float f) {
    union { float f; unsigned int i; } x; x.f = f;
    unsigned int r = (x.i + 0x7fffu + ((x.i >> 16) & 1u)) >> 16;
    return (unsigned short)r;
}

// load 8 consecutive fp32, round to bf16 fragment (two dwordx4 loads)
static __device__ __forceinline__ bf16x8 load8f(const float* __restrict__ p) {
    const floatx4 a = *(const floatx4*)p;
    const floatx4 b = *(const floatx4*)(p + 4);
    bf16x8 r;
#pragma unroll
    for (int i = 0; i < 4; ++i) r[i] = (short)f2bf(a[i]);
#pragma unroll
    for (int i = 0; i < 4; ++i) r[i + 4] = (short)f2bf(b[i]);
    return r;
}

// ---------------------------------------------------------------------------
// NT GEMM: C[M,N] = A[M,K] * W[N,K]^T + bias. W,bias fp32. fp32 accum.
// AMODE 0: A fp32.  AMODE 1: A bf16 (workspace).
// CMODE 0: C bf16 row-major. CMODE 1: C bf16 Vt[b][h][d][t]. CMODE 2: C fp32.
// 128x128 tile, BK=32, 256 threads (4 waves, 2x2 of 64x64 subtiles).
// ---------------------------------------------------------------------------
template<int AMODE, int CMODE>
__global__ __launch_bounds__(256, 2) void gemm_nt(
    const void* __restrict__ Av,
    const float* __restrict__ W,
    const float* __restrict__ bias,
    void* __restrict__ Cv,
    int M, int N, int K)
{
    __shared__ __align__(16) unsigned short As[128 * 32];
    __shared__ __align__(16) unsigned short Bs[128 * 32];

    const int tid  = threadIdx.x;
    const int wave = tid >> 6;
    const int lane = tid & 63;
    const int m0 = blockIdx.y * 128;
    const int n0 = blockIdx.x * 128;
    const int wm = (wave >> 1) * 64;
    const int wn = (wave & 1) * 64;
    const int q4 = lane >> 4;
    const int rr = lane & 15;

    // staging: chunk c covers rows [c*16, c*16+16) of the 128x32 tile
    const int lrow = lane >> 2;        // row within chunk (0..15)
    const int lk8  = (lane & 3) * 8;   // k-element offset (0,8,16,24)
    const int ar0 = wave * 16 + lrow;
    const int ar1 = (wave + 4) * 16 + lrow;

    floatx4 acc[4][4];
#pragma unroll
    for (int i = 0; i < 4; ++i)
#pragma unroll
        for (int j = 0; j < 4; ++j) acc[i][j] = (floatx4)0.0f;

    for (int k0 = 0; k0 < K; k0 += 32) {
        bf16x8 a0, a1;
        if (AMODE == 0) {
            const float* A = (const float*)Av;
            a0 = load8f(A + (size_t)(m0 + ar0) * K + k0 + lk8);
            a1 = load8f(A + (size_t)(m0 + ar1) * K + k0 + lk8);
        } else {
            const unsigned short* A = (const unsigned short*)Av;
            a0 = *(const bf16x8*)(A + (size_t)(m0 + ar0) * K + k0 + lk8);
            a1 = *(const bf16x8*)(A + (size_t)(m0 + ar1) * K + k0 + lk8);
        }
        bf16x8 b0 = load8f(W + (size_t)(n0 + ar0) * K + k0 + lk8);
        bf16x8 b1 = load8f(W + (size_t)(n0 + ar1) * K + k0 + lk8);
        __syncthreads();   // previous iteration's fragment reads complete
        *(bf16x8*)&As[ar0 * 32 + lk8] = a0;
        *(bf16x8*)&As[ar1 * 32 + lk8] = a1;
        *(bf16x8*)&Bs[ar0 * 32 + lk8] = b0;
        *(bf16x8*)&Bs[ar1 * 32 + lk8] = b1;
        __syncthreads();   // staging visible to all waves

        bf16x8 af[4], bfv[4];
#pragma unroll
        for (int mt = 0; mt < 4; ++mt)
            af[mt] = *(const bf16x8*)&As[(wm + mt * 16 + rr) * 32 + q4 * 8];
#pragma unroll
        for (int nt = 0; nt < 4; ++nt)
            bfv[nt] = *(const bf16x8*)&Bs[(wn + nt * 16 + rr) * 32 + q4 * 8];
#pragma unroll
        for (int mt = 0; mt < 4; ++mt)
#pragma unroll
            for (int nt = 0; nt < 4; ++nt)
                acc[mt][nt] = __builtin_amdgcn_mfma_f32_16x16x32_bf16(af[mt], bfv[nt], acc[mt][nt], 0, 0, 0);
    }

#pragma unroll
    for (int nt = 0; nt < 4; ++nt) {
        const int col = n0 + wn + nt * 16 + rr;
        const float bv = bias[col];
#pragma unroll
        for (int mt = 0; mt < 4; ++mt) {
#pragma unroll
            for (int r = 0; r < 4; ++r) {
                const int row = m0 + wm + mt * 16 + q4 * 4 + r;
                const float v = acc[mt][nt][r] + bv;
                if (CMODE == 0) {
                    ((unsigned short*)Cv)[(size_t)row * N + col] = f2bf(v);
                } else if (CMODE == 1) {
                    const int t = row >> 3, bb = row & 7;       // row = t*8 + b
                    const int h = col >> 8, d = col & 255;      // col = h*256 + d
                    ((unsigned short*)Cv)[((size_t)((bb * H_CNT + h) * DH + d)) * T_SEQ + t] = f2bf(v);
                } else {
                    ((float*)Cv)[(size_t)row * N + col] = v;
                }
            }
        }
    }
}

// ---------------------------------------------------------------------------
// Flash attention: grid (T/64, B*H), 256 threads. Wave w owns 16 Q rows.
// Q,K read as MFMA fragments straight from flat (T*B, F) bf16 layout; V from
// Vt[b][h][d][t]. Online softmax per row; P -> LDS -> A-fragment.
// ---------------------------------------------------------------------------
__global__ __launch_bounds__(256, 2) void attn_kernel(
    const unsigned short* __restrict__ Qb,
    const unsigned short* __restrict__ Kb,
    const unsigned short* __restrict__ Vt,
    unsigned short* __restrict__ Ob)
{
    __shared__ __align__(16) unsigned short Plds[4][16 * 32];
    const int tid  = threadIdx.x;
    const int wave = tid >> 6;
    const int lane = tid & 63;
    const int q4 = lane >> 4;
    const int rr = lane & 15;
    const int bh = blockIdx.y;
    const int b  = bh / H_CNT;
    const int h  = bh % H_CNT;
    const int qbase = blockIdx.x * 64 + wave * 16;

    // Q fragments: A[m=rr][k=q4*8+j] for 8 k-chunks of 32
    bf16x8 qf[8];
    {
        const unsigned short* qrow =
            Qb + ((size_t)((qbase + rr) * B_SZ + b)) * F_DIM + h * DH + q4 * 8;
#pragma unroll
        for (int kc = 0; kc < 8; ++kc)
            qf[kc] = *(const bf16x8*)(qrow + kc * 32);
    }

    float m_[4], l_[4];
#pragma unroll
    for (int r = 0; r < 4; ++r) { m_[r] = -1e9f; l_[r] = 0.0f; }
    floatx4 oacc[16];
#pragma unroll
    for (int nt = 0; nt < 16; ++nt) oacc[nt] = (floatx4)0.0f;

    const unsigned short* vbase = Vt + ((size_t)(b * H_CNT + h)) * DH * T_SEQ;

    for (int s0 = 0; s0 < T_SEQ; s0 += 32) {
        // S = Q K^T (16 x 32 per wave), fp32 acc
        floatx4 sacc[2] = { (floatx4)0.0f, (floatx4)0.0f };
#pragma unroll
        for (int nt = 0; nt < 2; ++nt) {
            const unsigned short* krow =
                Kb + ((size_t)((s0 + nt * 16 + rr) * B_SZ + b)) * F_DIM + h * DH + q4 * 8;
#pragma unroll
            for (int kc = 0; kc < 8; ++kc) {
                bf16x8 kf = *(const bf16x8*)(krow + kc * 32);
                sacc[nt] = __builtin_amdgcn_mfma_f32_16x16x32_bf16(qf[kc], kf, sacc[nt], 0, 0, 0);
            }
        }
        // online softmax over this 32-col chunk. Row (q4*4+r) is spread over
        // the 16 lanes of this quad -> xor-shuffle 1,2,4,8 stays in-group.
        float alpha[4];
#pragma unroll
        for (int r = 0; r < 4; ++r) {
            float s0v = sacc[0][r] * 0.125f;
            float s1v = sacc[1][r] * 0.125f;
            float cm = fmaxf(s0v, s1v);
            cm = fmaxf(cm, __shfl_xor(cm, 1));
            cm = fmaxf(cm, __shfl_xor(cm, 2));
            cm = fmaxf(cm, __shfl_xor(cm, 4));
            cm = fmaxf(cm, __shfl_xor(cm, 8));
            float mn = fmaxf(m_[r], cm);
            alpha[r] = __expf(m_[r] - mn);
            float p0 = __expf(s0v - mn);
            float p1 = __expf(s1v - mn);
            sacc[0][r] = p0; sacc[1][r] = p1;
            float rs = p0 + p1;
            rs += __shfl_xor(rs, 1);
            rs += __shfl_xor(rs, 2);
            rs += __shfl_xor(rs, 4);
            rs += __shfl_xor(rs, 8);
            l_[r] = alpha[r] * l_[r] + rs;
            m_[r] = mn;
        }
        // P (C-layout) -> LDS -> A-fragment layout
        unsigned short* pw = Plds[wave];
#pragma unroll
        for (int nt = 0; nt < 2; ++nt)
#pragma unroll
            for (int r = 0; r < 4; ++r)
                pw[(q4 * 4 + r) * 32 + nt * 16 + rr] = f2bf(sacc[nt][r]);
        __syncthreads();
        bf16x8 pf = *(const bf16x8*)&pw[rr * 32 + q4 * 8];

        // rescale O by alpha (same C-layout rows), then O += P * V
#pragma unroll
        for (int nt = 0; nt < 16; ++nt) {
#pragma unroll
            for (int r = 0; r < 4; ++r) oacc[nt][r] *= alpha[r];
        }
#pragma unroll
        for (int nt = 0; nt < 16; ++nt) {
            bf16x8 vf = *(const bf16x8*)(vbase + ((size_t)(nt * 16 + rr)) * T_SEQ + s0 + q4 * 8);
            oacc[nt] = __builtin_amdgcn_mfma_f32_16x16x32_bf16(pf, vf, oacc[nt], 0, 0, 0);
        }
        __syncthreads();
    }

#pragma unroll
    for (int r = 0; r < 4; ++r) {
        const float inv_l = 1.0f / fmaxf(l_[r], 1e-30f);
        const int t = qbase + q4 * 4 + r;
#pragma unroll
        for (int nt = 0; nt < 16; ++nt) {
            const int col = h * DH + nt * 16 + rr;
            const float v = oacc[nt][r] * inv_l;
            Ob[((size_t)(t * B_SZ + b)) * F_DIM + col] = f2bf(v);
        }
    }
}

// ---------------------------------------------------------------------------
extern "C" void kernel_launch(void* const* d_in, const int* in_sizes, int n_in,
                              void* d_out, int out_size, void* d_ws, size_t ws_size,
                              hipStream_t stream)
{
    const float* x  = (const float*)d_in[0];
    const float* Wq = (const float*)d_in[1];
    const float* bq = (const float*)d_in[2];
    const float* Wk = (const float*)d_in[3];
    const float* bk = (const float*)d_in[4];
    const float* Wv = (const float*)d_in[5];
    const float* bv = (const float*)d_in[6];
    const float* Wo = (const float*)d_in[7];
    const float* bo = (const float*)d_in[8];
    float* out = (float*)d_out;

    const int M = T_SEQ * B_SZ;   // 16384
    const int N = F_DIM, K = F_DIM;
    const size_t E = (size_t)M * F_DIM;   // 12.58M elems per bf16 buffer

    unsigned short* Qb = (unsigned short*)d_ws;   // bf16 Q, flat (M,F)
    unsigned short* Kb = Qb + E;                  // bf16 K, flat (M,F)
    unsigned short* Vt = Kb + E;                  // bf16 V^T, (B,H,DH,T)
    unsigned short* Ob = Vt + E;                  // bf16 attn out, flat (M,F)

    dim3 g(N / 128, M / 128), blk(256);
    gemm_nt<0, 0><<<g, blk, 0, stream>>>(x, Wq, bq, Qb, M, N, K);
    gemm_nt<0, 0><<<g, blk, 0, stream>>>(x, Wk, bk, Kb, M, N, K);
    gemm_nt<0, 1><<<g, blk, 0, stream>>>(x, Wv, bv, Vt, M, N, K);
    attn_kernel<<<dim3(T_SEQ / 64, B_SZ * H_CNT), blk, 0, stream>>>(Qb, Kb, Vt, Ob);
    gemm_nt<1, 2><<<g, blk, 0, stream>>>(Ob, Wo, bo, out, M, N, K);
}

// Round 4
// 562.452 us; speedup vs baseline: 1.9691x; 1.9691x over previous
//
#include <hip/hip_runtime.h>
#include <cstdint>
#include <cstddef>

#define T_SEQ 2048
#define B_SZ  8
#define F_DIM 768
#define H_CNT 3
#define DH    256

typedef float floatx4 __attribute__((ext_vector_type(4)));
typedef short bf16x8  __attribute__((ext_vector_type(8)));

static __device__ __forceinline__ unsigned short f2bf(float f) {
    union { float f; unsigned int i; } x; x.f = f;
    unsigned int r = (x.i + 0x7fffu + ((x.i >> 16) & 1u)) >> 16;
    return (unsigned short)r;
}

// load 8 consecutive fp32, round to bf16 fragment (two dwordx4 loads)
static __device__ __forceinline__ bf16x8 load8f(const float* __restrict__ p) {
    const floatx4 a = *(const floatx4*)p;
    const floatx4 b = *(const floatx4*)(p + 4);
    bf16x8 r;
#pragma unroll
    for (int i = 0; i < 4; ++i) r[i] = (short)f2bf(a[i]);
#pragma unroll
    for (int i = 0; i < 4; ++i) r[i + 4] = (short)f2bf(b[i]);
    return r;
}

// async global->LDS, 16B per lane; LDS dest = wave-uniform base + lane*16
#define ASYNC16(g, l) __builtin_amdgcn_global_load_lds( \
    (__attribute__((address_space(1))) void*)(void*)(g), \
    (__attribute__((address_space(3))) void*)(l), 16, 0, 0)

// ---------------------------------------------------------------------------
// NT GEMM: C = (A[M,K] * W[N,K]^T + bias) * scale. W,bias fp32. fp32 accum.
// AMODE 0: A fp32.  AMODE 1: A bf16 (workspace).
// CMODE 2: C fp32 row-major.
// CMODE 3: C bf16 in QK-fragment layout per head:
//          idx = head*(T*DH) + ((sblk*8+kc)*64 + q4*16+rr)*8 + e
//          where sblk=t>>4, rr=t&15, kc=d>>5, q4=(d>>3)&3, e=d&7
// CMODE 4: C bf16 in V-fragment layout per head:
//          idx = head*(T*DH) + ((skc*16+dblk)*64 + q4*16+rr)*8 + e
//          where skc=t>>5, q4=(t>>3)&3, e=t&7, dblk=d>>4, rr=d&15
// ---------------------------------------------------------------------------
template<int AMODE, int CMODE>
__global__ __launch_bounds__(256, 2) void gemm_nt(
    const void* __restrict__ Av,
    const float* __restrict__ W,
    const float* __restrict__ bias,
    void* __restrict__ Cv,
    int M, int N, int K, float scale)
{
    __shared__ __align__(16) unsigned short As[128 * 32];
    __shared__ __align__(16) unsigned short Bs[128 * 32];

    const int tid  = threadIdx.x;
    const int wave = tid >> 6;
    const int lane = tid & 63;
    const int m0 = blockIdx.y * 128;
    const int n0 = blockIdx.x * 128;
    const int wm = (wave >> 1) * 64;
    const int wn = (wave & 1) * 64;
    const int q4 = lane >> 4;
    const int rr = lane & 15;

    const int lrow = lane >> 2;        // row within chunk (0..15)
    const int lk8  = (lane & 3) * 8;   // k-element offset (0,8,16,24)
    const int ar0 = wave * 16 + lrow;
    const int ar1 = (wave + 4) * 16 + lrow;

    floatx4 acc[4][4];
#pragma unroll
    for (int i = 0; i < 4; ++i)
#pragma unroll
        for (int j = 0; j < 4; ++j) acc[i][j] = (floatx4)0.0f;

    for (int k0 = 0; k0 < K; k0 += 32) {
        bf16x8 a0, a1;
        if (AMODE == 0) {
            const float* A = (const float*)Av;
            a0 = load8f(A + (size_t)(m0 + ar0) * K + k0 + lk8);
            a1 = load8f(A + (size_t)(m0 + ar1) * K + k0 + lk8);
        } else {
            const unsigned short* A = (const unsigned short*)Av;
            a0 = *(const bf16x8*)(A + (size_t)(m0 + ar0) * K + k0 + lk8);
            a1 = *(const bf16x8*)(A + (size_t)(m0 + ar1) * K + k0 + lk8);
        }
        bf16x8 b0 = load8f(W + (size_t)(n0 + ar0) * K + k0 + lk8);
        bf16x8 b1 = load8f(W + (size_t)(n0 + ar1) * K + k0 + lk8);
        __syncthreads();   // previous iteration's fragment reads complete
        *(bf16x8*)&As[ar0 * 32 + lk8] = a0;
        *(bf16x8*)&As[ar1 * 32 + lk8] = a1;
        *(bf16x8*)&Bs[ar0 * 32 + lk8] = b0;
        *(bf16x8*)&Bs[ar1 * 32 + lk8] = b1;
        __syncthreads();   // staging visible to all waves

        bf16x8 af[4], bfv[4];
#pragma unroll
        for (int mt = 0; mt < 4; ++mt)
            af[mt] = *(const bf16x8*)&As[(wm + mt * 16 + rr) * 32 + q4 * 8];
#pragma unroll
        for (int nt = 0; nt < 4; ++nt)
            bfv[nt] = *(const bf16x8*)&Bs[(wn + nt * 16 + rr) * 32 + q4 * 8];
#pragma unroll
        for (int mt = 0; mt < 4; ++mt)
#pragma unroll
            for (int nt = 0; nt < 4; ++nt)
                acc[mt][nt] = __builtin_amdgcn_mfma_f32_16x16x32_bf16(af[mt], bfv[nt], acc[mt][nt], 0, 0, 0);
    }

#pragma unroll
    for (int nt = 0; nt < 4; ++nt) {
        const int col = n0 + wn + nt * 16 + rr;
        const float bv = bias[col];
#pragma unroll
        for (int mt = 0; mt < 4; ++mt) {
#pragma unroll
            for (int r = 0; r < 4; ++r) {
                const int row = m0 + wm + mt * 16 + q4 * 4 + r;
                const float v = (acc[mt][nt][r] + bv) * scale;
                if (CMODE == 2) {
                    ((float*)Cv)[(size_t)row * N + col] = v;
                } else {
                    const int t = row >> 3, bb = row & 7;   // row = t*B + b
                    const int h = col >> 8, d = col & 255;  // col = h*256 + d
                    const size_t hb = (size_t)(bb * H_CNT + h) * (T_SEQ * DH);
                    size_t idx;
                    if (CMODE == 3) {
                        const int sblk = t >> 4, rrq = t & 15;
                        const int kc = d >> 5, q4v = (d >> 3) & 3, e = d & 7;
                        idx = hb + (size_t)(((sblk * 8 + kc) * 64 + q4v * 16 + rrq) * 8 + e);
                    } else { // CMODE 4
                        const int skc = t >> 5, q4v = (t >> 3) & 3, e = t & 7;
                        const int dblk = d >> 4, rrq = d & 15;
                        idx = hb + (size_t)(((skc * 16 + dblk) * 64 + q4v * 16 + rrq) * 8 + e);
                    }
                    ((unsigned short*)Cv)[idx] = f2bf(v);
                }
            }
        }
    }
}

// ---------------------------------------------------------------------------
// Flash attention: grid (T/64, B*H), 256 threads, 3 blocks/CU (all 768
// co-resident). Wave w owns 16 Q rows (Q fragments resident in VGPRs).
// Per 32-s chunk: stage K (16 KB) + V (16 KB) fragment-contiguous via
// global_load_lds w16; QK -> online softmax -> P via wave-private LDS -> PV.
// ---------------------------------------------------------------------------
__global__ __launch_bounds__(256, 3) void attn_kernel(
    const unsigned short* __restrict__ Qf,
    const unsigned short* __restrict__ Kf,
    const unsigned short* __restrict__ Vf,
    unsigned short* __restrict__ Ob)
{
    __shared__ __align__(16) unsigned short Ks[8192];      // 2 sblk x 8 kc x 64 x 8
    __shared__ __align__(16) unsigned short Vs[8192];      // 16 dblk x 64 x 8
    __shared__ __align__(16) unsigned short Plds[4][512];  // per-wave 16x32

    const int tid  = threadIdx.x;
    const int wave = tid >> 6;
    const int lane = tid & 63;
    const int q4 = lane >> 4;
    const int rr = lane & 15;
    const int bh = blockIdx.y;
    const int b  = bh / H_CNT;
    const int h  = bh % H_CNT;
    const size_t hb = (size_t)bh * (T_SEQ * DH);

    // Q fragments (prescaled by 1/8 in projection): contiguous 1KB/wave loads
    const int qblk = blockIdx.x * 4 + wave;
    bf16x8 qf[8];
#pragma unroll
    for (int kc = 0; kc < 8; ++kc)
        qf[kc] = *(const bf16x8*)(Qf + hb + ((size_t)(qblk * 8 + kc) * 64 + lane) * 8);

    float m_[4], l_[4];
#pragma unroll
    for (int r = 0; r < 4; ++r) { m_[r] = -1e9f; l_[r] = 0.0f; }
    floatx4 oacc[16];
#pragma unroll
    for (int nt = 0; nt < 16; ++nt) oacc[nt] = (floatx4)0.0f;

    const int so = wave * 512 + lane * 8;   // staging offset (elems)

    for (int s0 = 0; s0 < T_SEQ; s0 += 32) {
        // stage K (2 sblks = 16 KB) and V (1 skc = 16 KB), both contiguous
        const unsigned short* kg = Kf + hb + (size_t)(s0 >> 4) * 4096;
        const unsigned short* vg = Vf + hb + (size_t)(s0 >> 5) * 8192;
#pragma unroll
        for (int rnd = 0; rnd < 4; ++rnd) {
            ASYNC16(kg + rnd * 2048 + so, (unsigned short*)Ks + rnd * 2048 + wave * 512);
            ASYNC16(vg + rnd * 2048 + so, (unsigned short*)Vs + rnd * 2048 + wave * 512);
        }
        __syncthreads();   // vmcnt(0) drain + barrier: tiles valid

        // S = Q K^T (16 x 32 per wave), fp32 acc; linear-in-lane ds_read_b128
        floatx4 sacc[2] = { (floatx4)0.0f, (floatx4)0.0f };
#pragma unroll
        for (int nt = 0; nt < 2; ++nt)
#pragma unroll
            for (int kc = 0; kc < 8; ++kc) {
                bf16x8 kf = *(const bf16x8*)&Ks[((nt * 8 + kc) * 64 + lane) * 8];
                sacc[nt] = __builtin_amdgcn_mfma_f32_16x16x32_bf16(qf[kc], kf, sacc[nt], 0, 0, 0);
            }

        // online softmax (scores already scaled): row q4*4+r across 16 lanes
        float alpha[4];
#pragma unroll
        for (int r = 0; r < 4; ++r) {
            float s0v = sacc[0][r];
            float s1v = sacc[1][r];
            float cm = fmaxf(s0v, s1v);
            cm = fmaxf(cm, __shfl_xor(cm, 1));
            cm = fmaxf(cm, __shfl_xor(cm, 2));
            cm = fmaxf(cm, __shfl_xor(cm, 4));
            cm = fmaxf(cm, __shfl_xor(cm, 8));
            float mn = fmaxf(m_[r], cm);
            alpha[r] = __expf(m_[r] - mn);
            float p0 = __expf(s0v - mn);
            float p1 = __expf(s1v - mn);
            sacc[0][r] = p0; sacc[1][r] = p1;
            float rs = p0 + p1;
            rs += __shfl_xor(rs, 1);
            rs += __shfl_xor(rs, 2);
            rs += __shfl_xor(rs, 4);
            rs += __shfl_xor(rs, 8);
            l_[r] = alpha[r] * l_[r] + rs;
            m_[r] = mn;
        }

        // P (C-layout) -> wave-private LDS -> A-fragment (no barrier needed)
        unsigned short* pw = Plds[wave];
#pragma unroll
        for (int nt = 0; nt < 2; ++nt)
#pragma unroll
            for (int r = 0; r < 4; ++r)
                pw[(q4 * 4 + r) * 32 + nt * 16 + rr] = f2bf(sacc[nt][r]);
        bf16x8 pf = *(const bf16x8*)&pw[rr * 32 + q4 * 8];

        // rescale O by alpha, then O += P * V
#pragma unroll
        for (int nt = 0; nt < 16; ++nt) {
#pragma unroll
            for (int r = 0; r < 4; ++r) oacc[nt][r] *= alpha[r];
        }
#pragma unroll
        for (int nt = 0; nt < 16; ++nt) {
            bf16x8 vf = *(const bf16x8*)&Vs[(nt * 64 + lane) * 8];
            oacc[nt] = __builtin_amdgcn_mfma_f32_16x16x32_bf16(pf, vf, oacc[nt], 0, 0, 0);
        }
        __syncthreads();   // all tile reads done before next chunk's staging
    }

#pragma unroll
    for (int r = 0; r < 4; ++r) {
        const float inv_l = 1.0f / fmaxf(l_[r], 1e-30f);
        const int t = qblk * 16 + q4 * 4 + r;
#pragma unroll
        for (int nt = 0; nt < 16; ++nt) {
            const int col = h * DH + nt * 16 + rr;
            const float v = oacc[nt][r] * inv_l;
            Ob[((size_t)(t * B_SZ + b)) * F_DIM + col] = f2bf(v);
        }
    }
}

// ---------------------------------------------------------------------------
extern "C" void kernel_launch(void* const* d_in, const int* in_sizes, int n_in,
                              void* d_out, int out_size, void* d_ws, size_t ws_size,
                              hipStream_t stream)
{
    const float* x  = (const float*)d_in[0];
    const float* Wq = (const float*)d_in[1];
    const float* bq = (const float*)d_in[2];
    const float* Wk = (const float*)d_in[3];
    const float* bk = (const float*)d_in[4];
    const float* Wv = (const float*)d_in[5];
    const float* bv = (const float*)d_in[6];
    const float* Wo = (const float*)d_in[7];
    const float* bo = (const float*)d_in[8];
    float* out = (float*)d_out;

    const int M = T_SEQ * B_SZ;   // 16384
    const int N = F_DIM, K = F_DIM;
    const size_t E = (size_t)M * F_DIM;   // 12.58M elems per bf16 buffer

    unsigned short* Qf = (unsigned short*)d_ws;   // bf16 Q, fragment layout
    unsigned short* Kb = Qf + E;                  // bf16 K, fragment layout
    unsigned short* Vb = Kb + E;                  // bf16 V, fragment layout
    unsigned short* Ob = Vb + E;                  // bf16 attn out, row-major

    dim3 g(N / 128, M / 128), blk(256);
    gemm_nt<0, 3><<<g, blk, 0, stream>>>(x, Wq, bq, Qf, M, N, K, 0.125f);
    gemm_nt<0, 3><<<g, blk, 0, stream>>>(x, Wk, bk, Kb, M, N, K, 1.0f);
    gemm_nt<0, 4><<<g, blk, 0, stream>>>(x, Wv, bv, Vb, M, N, K, 1.0f);
    attn_kernel<<<dim3(T_SEQ / 64, B_SZ * H_CNT), blk, 0, stream>>>(Qf, Kb, Vb, Ob);
    gemm_nt<1, 2><<<g, blk, 0, stream>>>(Ob, Wo, bo, out, M, N, K, 1.0f);
}

// Round 5
// 473.496 us; speedup vs baseline: 2.3390x; 1.1879x over previous
//
#include <hip/hip_runtime.h>
#include <cstdint>
#include <cstddef>

#define T_SEQ 2048
#define B_SZ  8
#define F_DIM 768
#define H_CNT 3
#define DH    256

typedef float floatx4 __attribute__((ext_vector_type(4)));
typedef short bf16x8  __attribute__((ext_vector_type(8)));

// round-half-up f32->bf16 (2 VALU); ties differ from RNE by 1 ulp (noise here)
static __device__ __forceinline__ unsigned short f2bf(float f) {
    union { float f; unsigned int i; } x; x.f = f;
    return (unsigned short)((x.i + 0x8000u) >> 16);
}
// pack two f32 -> u32 of two bf16 (lo=a, hi=b): 2 adds + v_perm
static __device__ __forceinline__ unsigned int pkbf(float a, float b) {
    union { float f; unsigned int i; } xa, xb; xa.f = a; xb.f = b;
    return __builtin_amdgcn_perm(xb.i + 0x8000u, xa.i + 0x8000u, 0x07060302u);
}
// load 8 consecutive fp32, convert to bf16x8 (packed converts)
static __device__ __forceinline__ bf16x8 cvt8(const float* __restrict__ p) {
    const floatx4 a = *(const floatx4*)p;
    const floatx4 b = *(const floatx4*)(p + 4);
    union { unsigned int u[4]; bf16x8 v; } r;
    r.u[0] = pkbf(a[0], a[1]); r.u[1] = pkbf(a[2], a[3]);
    r.u[2] = pkbf(b[0], b[1]); r.u[3] = pkbf(b[2], b[3]);
    return r.v;
}

// async global->LDS, 16B per lane; LDS dest = wave-uniform base + lane*16
#define ASYNC16(g, l) __builtin_amdgcn_global_load_lds( \
    (__attribute__((address_space(1))) void*)(void*)(g), \
    (__attribute__((address_space(3))) void*)(l), 16, 0, 0)

// ---------------------------------------------------------------------------
// NT GEMM: C = (A[M,K] * W[N,K]^T + bias) * scale. W,bias fp32. fp32 accum.
// AMODE 0: A fp32 (reg-convert staging).  AMODE 1: A bf16 (async LDS staging).
// CMODE 2: C fp32 row-major.
// CMODE 3: C bf16 in QK-fragment layout per head (see R4 notes).
// CMODE 4: C bf16 in V-fragment layout per head.
// ---------------------------------------------------------------------------
template<int AMODE, int CMODE>
__global__ __launch_bounds__(256, 2) void gemm_nt(
    const void* __restrict__ Av,
    const float* __restrict__ W,
    const float* __restrict__ bias,
    void* __restrict__ Cv,
    int M, int N, int K, float scale)
{
    __shared__ __align__(16) unsigned short As[128 * 32];
    __shared__ __align__(16) unsigned short Bs[128 * 32];

    const int tid  = threadIdx.x;
    const int wave = tid >> 6;
    const int lane = tid & 63;
    const int m0 = blockIdx.y * 128;
    const int n0 = blockIdx.x * 128;
    const int wm = (wave >> 1) * 64;
    const int wn = (wave & 1) * 64;
    const int q4 = lane >> 4;
    const int rr = lane & 15;

    const int lrow = lane >> 2;        // row within 16-row chunk
    const int lk8  = (lane & 3) * 8;   // k-element offset
    const int ar0 = wave * 16 + lrow;
    const int ar1 = (wave + 4) * 16 + lrow;

    floatx4 acc[4][4];
#pragma unroll
    for (int i = 0; i < 4; ++i)
#pragma unroll
        for (int j = 0; j < 4; ++j) acc[i][j] = (floatx4)0.0f;

    for (int k0 = 0; k0 < K; k0 += 32) {
        bf16x8 a0, a1;
        if (AMODE == 0) {
            const float* A = (const float*)Av;
            a0 = cvt8(A + (size_t)(m0 + ar0) * K + k0 + lk8);
            a1 = cvt8(A + (size_t)(m0 + ar1) * K + k0 + lk8);
        }
        bf16x8 b0 = cvt8(W + (size_t)(n0 + ar0) * K + k0 + lk8);
        bf16x8 b1 = cvt8(W + (size_t)(n0 + ar1) * K + k0 + lk8);
        __syncthreads();   // previous iteration's fragment reads complete
        if (AMODE == 0) {
            *(bf16x8*)&As[ar0 * 32 + lk8] = a0;
            *(bf16x8*)&As[ar1 * 32 + lk8] = a1;
        } else {
            const unsigned short* A = (const unsigned short*)Av;
            ASYNC16(A + (size_t)(m0 + ar0) * K + k0 + lk8, (unsigned short*)As + wave * 512);
            ASYNC16(A + (size_t)(m0 + ar1) * K + k0 + lk8, (unsigned short*)As + (wave + 4) * 512);
        }
        *(bf16x8*)&Bs[ar0 * 32 + lk8] = b0;
        *(bf16x8*)&Bs[ar1 * 32 + lk8] = b1;
        __syncthreads();   // staging visible (drains vmcnt for async path)

        bf16x8 af[4], bfv[4];
#pragma unroll
        for (int mt = 0; mt < 4; ++mt)
            af[mt] = *(const bf16x8*)&As[(wm + mt * 16 + rr) * 32 + q4 * 8];
#pragma unroll
        for (int nt = 0; nt < 4; ++nt)
            bfv[nt] = *(const bf16x8*)&Bs[(wn + nt * 16 + rr) * 32 + q4 * 8];
#pragma unroll
        for (int mt = 0; mt < 4; ++mt)
#pragma unroll
            for (int nt = 0; nt < 4; ++nt)
                acc[mt][nt] = __builtin_amdgcn_mfma_f32_16x16x32_bf16(af[mt], bfv[nt], acc[mt][nt], 0, 0, 0);
    }

#pragma unroll
    for (int nt = 0; nt < 4; ++nt) {
        const int col = n0 + wn + nt * 16 + rr;
        const float bv = bias[col];
#pragma unroll
        for (int mt = 0; mt < 4; ++mt) {
#pragma unroll
            for (int r = 0; r < 4; ++r) {
                const int row = m0 + wm + mt * 16 + q4 * 4 + r;
                const float v = (acc[mt][nt][r] + bv) * scale;
                if (CMODE == 2) {
                    ((float*)Cv)[(size_t)row * N + col] = v;
                } else {
                    const int t = row >> 3, bb = row & 7;   // row = t*B + b
                    const int h = col >> 8, d = col & 255;  // col = h*256 + d
                    const size_t hb = (size_t)(bb * H_CNT + h) * (T_SEQ * DH);
                    size_t idx;
                    if (CMODE == 3) {
                        const int sblk = t >> 4, rrq = t & 15;
                        const int kc = d >> 5, q4v = (d >> 3) & 3, e = d & 7;
                        idx = hb + (size_t)(((sblk * 8 + kc) * 64 + q4v * 16 + rrq) * 8 + e);
                    } else { // CMODE 4
                        const int skc = t >> 5, q4v = (t >> 3) & 3, e = t & 7;
                        const int dblk = d >> 4, rrq = d & 15;
                        idx = hb + (size_t)(((skc * 16 + dblk) * 64 + q4v * 16 + rrq) * 8 + e);
                    }
                    ((unsigned short*)Cv)[idx] = f2bf(v);
                }
            }
        }
    }
}

// ---------------------------------------------------------------------------
// Flash attention v2: grid (T/64, B*H), 128 threads (2 waves). Wave owns
// 32 Q rows. Scores computed TRANSPOSED (S^T = K Q^T): per lane, each Q-col's
// s-values sit in registers -> softmax = in-reg reduce + 2 shuffles.
// O accumulated transposed (O^T = V^T P). K/V tiles staged via
// global_load_lds w16; P via padded per-wave LDS tile.
// ---------------------------------------------------------------------------
__global__ __launch_bounds__(128, 2) void attn_kernel(
    const unsigned short* __restrict__ Qf,
    const unsigned short* __restrict__ Kf,
    const unsigned short* __restrict__ Vf,
    unsigned short* __restrict__ Ob)
{
    __shared__ __align__(16) unsigned short Ks[8192];       // [sblk2][kc8][64][8]
    __shared__ __align__(16) unsigned short Vs[8192];       // [dblk16][64][8]
    __shared__ __align__(16) unsigned short Ps[2][32 * 40]; // per-wave P[q][s], pad 8

    const int tid  = threadIdx.x;
    const int wave = tid >> 6;
    const int lane = tid & 63;
    const int q4 = lane >> 4;
    const int rr = lane & 15;
    const int bh = blockIdx.y;
    const int b  = bh / H_CNT;
    const int h  = bh % H_CNT;
    const size_t hb = (size_t)bh * (T_SEQ * DH);

    // wave's 32 Q rows = two 16-row fragment tiles sb0, sb0+1 (prescaled 1/8)
    const int sb0 = blockIdx.x * 4 + wave * 2;
    bf16x8 qf_[2][8];
#pragma unroll
    for (int qnt = 0; qnt < 2; ++qnt)
#pragma unroll
        for (int kc = 0; kc < 8; ++kc)
            qf_[qnt][kc] = *(const bf16x8*)(Qf + hb + ((size_t)((sb0 + qnt) * 8 + kc) * 64 + lane) * 8);

    float m_[2] = { -1e9f, -1e9f }, l_[2] = { 0.0f, 0.0f };
    floatx4 oacc[16][2];
#pragma unroll
    for (int dt = 0; dt < 16; ++dt)
#pragma unroll
        for (int qnt = 0; qnt < 2; ++qnt) oacc[dt][qnt] = (floatx4)0.0f;

    const int sbase = wave * 4096 + lane * 8;   // staging src/dst offset (elems)

    for (int s0 = 0; s0 < T_SEQ; s0 += 32) {
        const unsigned short* kg = Kf + hb + (size_t)(s0 >> 4) * 4096;
        const unsigned short* vg = Vf + hb + (size_t)(s0 >> 5) * 8192;
#pragma unroll
        for (int rnd = 0; rnd < 8; ++rnd) {
            ASYNC16(kg + sbase + rnd * 512, (unsigned short*)Ks + wave * 4096 + rnd * 512);
            ASYNC16(vg + sbase + rnd * 512, (unsigned short*)Vs + wave * 4096 + rnd * 512);
        }
        __syncthreads();   // vmcnt drain: tiles valid

        // S^T = K Q^T : D[s][q], tiles [smt][qnt]
        floatx4 sacc[2][2];
#pragma unroll
        for (int i = 0; i < 2; ++i)
#pragma unroll
            for (int j = 0; j < 2; ++j) sacc[i][j] = (floatx4)0.0f;
#pragma unroll
        for (int kc = 0; kc < 8; ++kc) {
            bf16x8 k0 = *(const bf16x8*)&Ks[((0 * 8 + kc) * 64 + lane) * 8];
            bf16x8 k1 = *(const bf16x8*)&Ks[((1 * 8 + kc) * 64 + lane) * 8];
            sacc[0][0] = __builtin_amdgcn_mfma_f32_16x16x32_bf16(k0, qf_[0][kc], sacc[0][0], 0, 0, 0);
            sacc[0][1] = __builtin_amdgcn_mfma_f32_16x16x32_bf16(k0, qf_[1][kc], sacc[0][1], 0, 0, 0);
            sacc[1][0] = __builtin_amdgcn_mfma_f32_16x16x32_bf16(k1, qf_[0][kc], sacc[1][0], 0, 0, 0);
            sacc[1][1] = __builtin_amdgcn_mfma_f32_16x16x32_bf16(k1, qf_[1][kc], sacc[1][1], 0, 0, 0);
        }

        // online softmax: per lane, q-col = qnt*16+rr; its 8 s-values are in
        // regs (smt, r); cross-quad combine via xor 16 / xor 32.
        float alpha[2];
        int upd = 0;
#pragma unroll
        for (int qnt = 0; qnt < 2; ++qnt) {
            float cm = sacc[0][qnt][0];
#pragma unroll
            for (int smt = 0; smt < 2; ++smt)
#pragma unroll
                for (int r = 0; r < 4; ++r) cm = fmaxf(cm, sacc[smt][qnt][r]);
            cm = fmaxf(cm, __shfl_xor(cm, 16));
            cm = fmaxf(cm, __shfl_xor(cm, 32));
            const float mn = fmaxf(m_[qnt], cm);
            alpha[qnt] = __expf(m_[qnt] - mn);
            float rs = 0.0f;
#pragma unroll
            for (int smt = 0; smt < 2; ++smt)
#pragma unroll
                for (int r = 0; r < 4; ++r) {
                    const float p = __expf(sacc[smt][qnt][r] - mn);
                    sacc[smt][qnt][r] = p; rs += p;
                }
            rs += __shfl_xor(rs, 16);
            rs += __shfl_xor(rs, 32);
            l_[qnt] = alpha[qnt] * l_[qnt] + rs;
            upd |= (mn > m_[qnt]);
            m_[qnt] = mn;
        }

        // P (S^T C-layout) -> per-wave LDS tile P[q][s] (stride 40, b128-aligned reads)
        unsigned short* pw = Ps[wave];
#pragma unroll
        for (int qnt = 0; qnt < 2; ++qnt)
#pragma unroll
            for (int smt = 0; smt < 2; ++smt)
#pragma unroll
                for (int r = 0; r < 4; ++r)
                    pw[(qnt * 16 + rr) * 40 + smt * 16 + q4 * 4 + r] = f2bf(sacc[smt][qnt][r]);
        bf16x8 pf0 = *(const bf16x8*)&pw[(0 * 16 + rr) * 40 + q4 * 8];
        bf16x8 pf1 = *(const bf16x8*)&pw[(1 * 16 + rr) * 40 + q4 * 8];

        // O rescale only when some row-max moved (wave-uniform skip)
        if (__any(upd)) {
#pragma unroll
            for (int dt = 0; dt < 16; ++dt)
#pragma unroll
                for (int qnt = 0; qnt < 2; ++qnt)
#pragma unroll
                    for (int r = 0; r < 4; ++r) oacc[dt][qnt][r] *= alpha[qnt];
        }

        // O^T += V^T P : A = V^T d-tiles, B = P q-tiles
#pragma unroll
        for (int dt = 0; dt < 16; ++dt) {
            bf16x8 vf = *(const bf16x8*)&Vs[(dt * 64 + lane) * 8];
            oacc[dt][0] = __builtin_amdgcn_mfma_f32_16x16x32_bf16(vf, pf0, oacc[dt][0], 0, 0, 0);
            oacc[dt][1] = __builtin_amdgcn_mfma_f32_16x16x32_bf16(vf, pf1, oacc[dt][1], 0, 0, 0);
        }
        __syncthreads();   // tile reads done before next chunk's staging
    }

    // epilogue: lane holds (d = dt*16 + q4*4 + r, q = qnt*16 + rr); pack r-pairs
#pragma unroll
    for (int qnt = 0; qnt < 2; ++qnt) {
        const float inv_l = 1.0f / fmaxf(l_[qnt], 1e-30f);
        const int t = blockIdx.x * 64 + wave * 32 + qnt * 16 + rr;
        unsigned short* orow = Ob + (size_t)(t * B_SZ + b) * F_DIM + h * DH;
#pragma unroll
        for (int dt = 0; dt < 16; ++dt) {
#pragma unroll
            for (int rp = 0; rp < 2; ++rp) {
                const unsigned int w = pkbf(oacc[dt][qnt][rp * 2] * inv_l,
                                            oacc[dt][qnt][rp * 2 + 1] * inv_l);
                *(unsigned int*)(orow + dt * 16 + q4 * 4 + rp * 2) = w;
            }
        }
    }
}

// ---------------------------------------------------------------------------
extern "C" void kernel_launch(void* const* d_in, const int* in_sizes, int n_in,
                              void* d_out, int out_size, void* d_ws, size_t ws_size,
                              hipStream_t stream)
{
    const float* x  = (const float*)d_in[0];
    const float* Wq = (const float*)d_in[1];
    const float* bq = (const float*)d_in[2];
    const float* Wk = (const float*)d_in[3];
    const float* bk = (const float*)d_in[4];
    const float* Wv = (const float*)d_in[5];
    const float* bv = (const float*)d_in[6];
    const float* Wo = (const float*)d_in[7];
    const float* bo = (const float*)d_in[8];
    float* out = (float*)d_out;

    const int M = T_SEQ * B_SZ;   // 16384
    const int N = F_DIM, K = F_DIM;
    const size_t E = (size_t)M * F_DIM;

    unsigned short* Qf = (unsigned short*)d_ws;   // bf16 Q, fragment layout
    unsigned short* Kb = Qf + E;                  // bf16 K, fragment layout
    unsigned short* Vb = Kb + E;                  // bf16 V, fragment layout
    unsigned short* Ob = Vb + E;                  // bf16 attn out, row-major

    dim3 g(N / 128, M / 128), blk(256);
    gemm_nt<0, 3><<<g, blk, 0, stream>>>(x, Wq, bq, Qf, M, N, K, 0.125f);
    gemm_nt<0, 3><<<g, blk, 0, stream>>>(x, Wk, bk, Kb, M, N, K, 1.0f);
    gemm_nt<0, 4><<<g, blk, 0, stream>>>(x, Wv, bv, Vb, M, N, K, 1.0f);
    attn_kernel<<<dim3(T_SEQ / 64, B_SZ * H_CNT), dim3(128), 0, stream>>>(Qf, Kb, Vb, Ob);
    gemm_nt<1, 2><<<g, blk, 0, stream>>>(Ob, Wo, bo, out, M, N, K, 1.0f);
}